// Round 7
// baseline (218.670 us; speedup 1.0000x reference)
//
#include <hip/hip_runtime.h>
#include <hip/hip_bf16.h>

// B=4096, C=32, P=196, ENC=512, ATT=128. fp32 I/O.
// R2: k0 folded into k1 (in-register hi/lo split of B); k1b float4 (-3us).
// R5: k2 rewritten -- img staged RAW fp32 [c][p] linear into LDS via
// global_load_lds DMA (no VGPR round trip, no transpose pass); 2 batches
// per block (grid 2048), double-buffered: batch n+1's DMA issued before
// batch n's compute; __syncthreads' implicit vmcnt(0) drain is the DMA
// fence. Phase B builds bf16 A-frags from LDS fp32 (RNE, same values as
// before -> scores bit-identical); Phase D uses fp32 img (more accurate).
// LDS 51.6 KB -> 3 blocks/CU, launch_bounds(256,3).
// LESSONS: (R5/R6 prev) waves/EU >= 6 => scratch-spill storm; keep VGPR
// headroom via low min-waves. (R9 prev) harness poison+restore ~95-150us
// in-window; fills monopolize rocprof top-5 -> attribute via dur_us only.
// (R10 prev) runtime-loop partial-reduce prologue in k2 = +35us; k1b stays.

typedef __attribute__((ext_vector_type(8))) short short8;
typedef __attribute__((ext_vector_type(8))) __bf16 bf16x8;
typedef __attribute__((ext_vector_type(4))) float floatx4;
typedef __attribute__((ext_vector_type(4))) unsigned int uint4v;

#define K2E 2.8853900817779268f   // 2*log2(e)

#if __has_builtin(__builtin_amdgcn_exp2f)
#define EXP2F(x) __builtin_amdgcn_exp2f(x)
#else
#define EXP2F(x) __expf(0.6931471805599453f * (x))
#endif

typedef __attribute__((address_space(3))) unsigned int as3_u32;
typedef const __attribute__((address_space(1))) unsigned int as1_u32;

static __device__ __forceinline__ float bf2f(unsigned short u) {
    union { unsigned int i; float f; } v; v.i = ((unsigned int)u) << 16; return v.f;
}
static __device__ __forceinline__ unsigned short f2bf(float f) {
    union { float f; unsigned int i; } v; v.f = f;
    unsigned int r = v.i + 0x7FFFu + ((v.i >> 16) & 1u);  // RNE
    return (unsigned short)(r >> 16);
}
static __device__ __forceinline__ float sigmoid_rcp(float x) {
    return __builtin_amdgcn_rcpf(1.0f + __expf(-x));
}
// Truncation hi/lo split of 8 contiguous fp32 (16B-aligned).
static __device__ __forceinline__ void split_trunc8(const float* src, bf16x8* hi, bf16x8* lo) {
    uint4v u0 = *(const uint4v*)src;
    uint4v u1 = *(const uint4v*)(src + 4);
    unsigned int fb[8], lb[8];
#pragma unroll
    for (int j = 0; j < 4; j++) { fb[j] = u0[j]; fb[4 + j] = u1[j]; }
#pragma unroll
    for (int k = 0; k < 8; k++) {
        float x = __uint_as_float(fb[k]);
        float h = __uint_as_float(fb[k] & 0xFFFF0000u);
        lb[k] = __float_as_uint(x - h);               // exact residual
    }
    uint4v hp, lp;
#pragma unroll
    for (int j = 0; j < 4; j++) {
        hp[j] = __builtin_amdgcn_perm(fb[2 * j + 1], fb[2 * j], 0x07060302u);
        lp[j] = __builtin_amdgcn_perm(lb[2 * j + 1], lb[2 * j], 0x07060302u);
    }
    *hi = __builtin_bit_cast(bf16x8, hp);
    *lo = __builtin_bit_cast(bf16x8, lp);
}

// ---------------------------------------------------------------------------
// k1: partial GEMM hidden @ [U_w;fb_w]^T, split-K (ws-gated), in-register
// hi/lo split of BOTH operands from fp32. Side-job: Whi = bf16(K2E*W_w).
// ---------------------------------------------------------------------------
__global__ __launch_bounds__(256) void k1_gemm(
    const float* __restrict__ hidden,
    const float* __restrict__ U_w, const float* __restrict__ fb_w,
    const float* __restrict__ W_w,
    const float* __restrict__ U_b, const float* __restrict__ W_b,
    const float* __restrict__ fb_b,
    float* __restrict__ uh_out, float* __restrict__ beta_out,
    unsigned short* __restrict__ Whi,
    float* __restrict__ partial, int nsplit, int direct)
{
    __shared__ float s_part[4 * 2560];
    const int tid = threadIdx.x;
    {
        const int gi = blockIdx.x * 256 + tid;
        if (gi < 4096) Whi[gi] = f2bf(W_w[gi] * K2E);
    }
    const int wave = tid >> 6, lane = tid & 63, quad = lane >> 4, l16 = lane & 15;
    const int mtile = blockIdx.x / nsplit;
    const int kblock = 512 / nsplit;
    const int ks0 = (blockIdx.x % nsplit) * kblock + wave * (kblock >> 2);
    const int ksteps = kblock >> 7;
    const int arow = mtile * 16 + l16;

    floatx4 acc[10];
#pragma unroll
    for (int i = 0; i < 10; i++) acc[i] = (floatx4)(0.0f);

    for (int ksi = 0; ksi < ksteps; ksi++) {
        const int e0 = ks0 + ksi * 32 + quad * 8;
        bf16x8 ah, al;
        split_trunc8(hidden + (size_t)arow * 512 + e0, &ah, &al);
#pragma unroll
        for (int n = 0; n < 10; n++) {
            const float* bsrc = (n < 8)
                ? (U_w  + (size_t)(n * 16 + l16) * 512 + e0)
                : (fb_w + (size_t)((n - 8) * 16 + l16) * 512 + e0);
            bf16x8 bh, bl;
            split_trunc8(bsrc, &bh, &bl);
            acc[n] = __builtin_amdgcn_mfma_f32_16x16x32_bf16(ah, bl, acc[n], 0, 0, 0);
            acc[n] = __builtin_amdgcn_mfma_f32_16x16x32_bf16(al, bh, acc[n], 0, 0, 0);
            acc[n] = __builtin_amdgcn_mfma_f32_16x16x32_bf16(ah, bh, acc[n], 0, 0, 0);
        }
    }
#pragma unroll
    for (int n = 0; n < 10; n++)
#pragma unroll
        for (int r = 0; r < 4; r++)
            s_part[wave * 2560 + (quad * 4 + r) * 160 + n * 16 + l16] = acc[n][r];
    __syncthreads();

#pragma unroll
    for (int j = 0; j < 10; j++) {
        const int i = tid + j * 256;
        float v = s_part[i] + s_part[2560 + i] + s_part[5120 + i] + s_part[7680 + i];
        if (direct) {
            const int m = mtile * 16 + i / 160, col = i % 160;
            if (col < 128) uh_out[(size_t)m * 128 + col] = K2E * (v + U_b[col] + W_b[col]);
            else beta_out[(size_t)m * 32 + (col - 128)] = sigmoid_rcp(v + fb_b[col - 128]);
        } else {
            partial[(size_t)blockIdx.x * 2560 + i] = v;
        }
    }
}

// k1b: float4-vectorized split-K reduce. 640 blocks x 256 thr.
__global__ __launch_bounds__(256) void k1b_reduce(
    const float* __restrict__ partial,
    const float* __restrict__ U_b, const float* __restrict__ W_b,
    const float* __restrict__ fb_b,
    float* __restrict__ uh_out, float* __restrict__ beta_out, int nsplit)
{
    const int idx = blockIdx.x * 256 + threadIdx.x;
    const int mt = idx / 640;
    const int r4 = (idx - mt * 640) * 4;
    floatx4 v = (floatx4)(0.0f);
    for (int s = 0; s < nsplit; s++) {
        const floatx4 p = *(const floatx4*)(partial + (size_t)(mt * nsplit + s) * 2560 + r4);
#pragma unroll
        for (int j = 0; j < 4; j++) v[j] += p[j];
    }
    const int m = mt * 16 + r4 / 160, col = r4 % 160;
    if (col < 128) {
        const floatx4 ub = *(const floatx4*)(U_b + col);
        const floatx4 wb = *(const floatx4*)(W_b + col);
        floatx4 o;
#pragma unroll
        for (int j = 0; j < 4; j++) o[j] = K2E * (v[j] + ub[j] + wb[j]);
        *(floatx4*)(uh_out + (size_t)m * 128 + col) = o;
    } else {
        const floatx4 fb = *(const floatx4*)(fb_b + (col - 128));
        floatx4 o;
#pragma unroll
        for (int j = 0; j < 4; j++) o[j] = sigmoid_rcp(v[j] + fb[j]);
        *(floatx4*)(beta_out + (size_t)m * 32 + (col - 128)) = o;
    }
}

// ---------------------------------------------------------------------------
// k2 (R5): grid 2048, 2 batches/block (b, b+2048), double-buffered fp32 img
// in LDS via global_load_lds DMA. Per batch: Phase B (MFMA scores + tanh via
// exp2, max-free softmax), Phase D (fp32 context). 3 barriers per batch.
// ---------------------------------------------------------------------------
#define SRAW 6284   // 6272 staged dwords + 12 zeroed pad (covers c=31,p<=207)

// Stage img[bb] (6272 dwords) into LDS linear [c][p]. 98 chunks of 64 dwords;
// wave w issues chunks w, w+4, ... LDS dest = uniform base + lane*4 (HW rule).
static __device__ __forceinline__ void stage_img(
    const float* __restrict__ img, int bb, float* dst, int wave, int lane)
{
    const unsigned int* g = (const unsigned int*)(img + (size_t)bb * 6272);
    for (int ch = wave; ch < 98; ch += 4) {
        __builtin_amdgcn_global_load_lds(
            (as1_u32*)(g + ch * 64 + lane),
            (as3_u32*)((unsigned int*)dst + ch * 64),
            4, 0, 0);
    }
}

static __device__ __forceinline__ void attn_batch(
    int bb, const float* __restrict__ sraw,
    const unsigned short* __restrict__ Whi,
    const float* __restrict__ beta, float* __restrict__ out,
    float* s_score, float* s_red, float (*s_ctx)[32],
    const float* uaR, const float* va2R, float sv,
    int tid, int wave, int lane, int quad, int l16)
{
    // ---- Phase B: scores. |score| <= sum|v| (~5) -> max-free softmax. ----
    float esum = 0.0f;
    for (int mt = wave; mt < 13; mt += 4) {
        // build bf16 A-frag from fp32 LDS (RNE -> same values as old path)
        unsigned int hb[8];
#pragma unroll
        for (int j = 0; j < 8; j++) {
            unsigned int u = __float_as_uint(sraw[(quad * 8 + j) * 196 + mt * 16 + l16]);
            hb[j] = u + 0x7FFFu + ((u >> 16) & 1u);
        }
        uint4v hp;
#pragma unroll
        for (int j = 0; j < 4; j++)
            hp[j] = __builtin_amdgcn_perm(hb[2 * j + 1], hb[2 * j], 0x07060302u);
        bf16x8 a = __builtin_bit_cast(bf16x8, hp);

        float sc4[4] = {0.f, 0.f, 0.f, 0.f};
#pragma unroll
        for (int nt = 0; nt < 8; nt++) {
            bf16x8 bh = *(const bf16x8*)(Whi + (nt * 16 + l16) * 32 + quad * 8);
            const float ua = uaR[nt];
            floatx4 d = {ua, ua, ua, ua};
            d = __builtin_amdgcn_mfma_f32_16x16x32_bf16(a, bh, d, 0, 0, 0);
#pragma unroll
            for (int r = 0; r < 4; r++) {
                float e = EXP2F(d[r]);                         // e^{2x}
                float rr = __builtin_amdgcn_rcpf(1.0f + e);
                sc4[r] = __builtin_fmaf(va2R[nt], rr, sc4[r]); // -2 v_a r
            }
        }
#pragma unroll
        for (int r = 0; r < 4; r++) {
            float s = sc4[r];
            s += __shfl_xor(s, 1); s += __shfl_xor(s, 2);
            s += __shfl_xor(s, 4); s += __shfl_xor(s, 8);
            const int p = mt * 16 + quad * 4 + r;
            if (l16 == 0 && p < 196) {
                float e = __expf(sv + s);
                s_score[p] = e;
                esum += e;
            }
        }
    }
    esum += __shfl_xor(esum, 16);
    esum += __shfl_xor(esum, 32);
    if (lane == 0) s_red[wave] = esum;
    __syncthreads();   // scores + per-wave sums ready

    const float tot = s_red[0] + s_red[1] + s_red[2] + s_red[3];
    const float rtot = __builtin_amdgcn_rcpf(tot);
    if (tid < 196)
        out[131072 + (size_t)bb * 196 + tid] = s_score[tid] * rtot;

    // ---- Phase D: context from fp32 img ----
    {
        const int c = lane & 31;
        const int po = wave * 2 + (lane >> 5);   // 0..7
        float acc = 0.0f;
#pragma unroll 5
        for (int j = 0; j < 25; j++) {
            const int p = po + j * 8;            // <=199; score rows >=196 are 0
            acc = __builtin_fmaf(sraw[c * 196 + p], s_score[p], acc);
        }
        acc += __shfl_xor(acc, 32);
        if ((lane >> 5) == 0) s_ctx[wave][c] = acc;
    }
    __syncthreads();   // ctx partials ready
    if (tid < 32) {
        const float v = s_ctx[0][tid] + s_ctx[1][tid] + s_ctx[2][tid] + s_ctx[3][tid];
        out[(size_t)bb * 32 + tid] = v * rtot * beta[(size_t)bb * 32 + tid];
    }
}

__global__ __launch_bounds__(256, 3) void k2_attn(
    const float* __restrict__ img,            // [4096][32][196]
    const unsigned short* __restrict__ Whi,   // [128][32] bf16 (pre-scaled K2E)
    const float* __restrict__ v_w,            // [128]
    const float* __restrict__ uh,             // [4096][128] (scaled K2E, biases in)
    const float* __restrict__ beta,           // [4096][32]
    float* __restrict__ out)
{
    __shared__ __align__(16) float s_raw[2][SRAW];   // 50.3 KB
    __shared__ float s_score[208];
    __shared__ float s_red[4];
    __shared__ float s_ctx[4][32];

    const int tid = threadIdx.x;
    const int b = blockIdx.x;                 // 0..2047; batches b and b+2048
    const int wave = tid >> 6, lane = tid & 63, quad = lane >> 4, l16 = lane & 15;

    // prologue: zero unstaged LDS pads + score pad; DMA batch 0; setup
    if (tid < 12) { s_raw[0][6272 + tid] = 0.0f; s_raw[1][6272 + tid] = 0.0f; }
    if (tid >= 196 && tid < 208) s_score[tid] = 0.0f;
    stage_img(img, b, s_raw[0], wave, lane);

    float va2R[8], sv = 0.0f;
#pragma unroll
    for (int nt = 0; nt < 8; nt++) {
        float v = v_w[nt * 16 + l16];
        sv += v;
        va2R[nt] = -2.0f * v;
    }
    sv += __shfl_xor(sv, 1); sv += __shfl_xor(sv, 2);
    sv += __shfl_xor(sv, 4); sv += __shfl_xor(sv, 8);

    float uaR[8];
#pragma unroll
    for (int nt = 0; nt < 8; nt++) uaR[nt] = uh[(size_t)b * 128 + nt * 16 + l16];

    __syncthreads();   // implicit vmcnt(0): buf0 DMA + pads complete

    // prefetch batch 1 into buf1 (flies under batch-0 compute)
    stage_img(img, b + 2048, s_raw[1], wave, lane);

    attn_batch(b, s_raw[0], Whi, beta, out, s_score, s_red, s_ctx,
               uaR, va2R, sv, tid, wave, lane, quad, l16);

#pragma unroll
    for (int nt = 0; nt < 8; nt++)
        uaR[nt] = uh[(size_t)(b + 2048) * 128 + nt * 16 + l16];

    __syncthreads();   // drains buf1 DMA; guards s_score/s_red/s_ctx reuse

    attn_batch(b + 2048, s_raw[1], Whi, beta, out, s_score, s_red, s_ctx,
               uaR, va2R, sv, tid, wave, lane, quad, l16);
}

extern "C" void kernel_launch(void* const* d_in, const int* in_sizes, int n_in,
                              void* d_out, int out_size, void* d_ws, size_t ws_size,
                              hipStream_t stream) {
    const float* img    = (const float*)d_in[0];
    const float* hidden = (const float*)d_in[1];
    const float* W_w    = (const float*)d_in[2];
    const float* W_b    = (const float*)d_in[3];
    const float* U_w    = (const float*)d_in[4];
    const float* U_b    = (const float*)d_in[5];
    const float* v_w    = (const float*)d_in[6];
    // d_in[7] = v_b: cancels in softmax
    const float* fb_w   = (const float*)d_in[8];
    const float* fb_b   = (const float*)d_in[9];
    float* out = (float*)d_out;

    float* uh_ws   = (float*)d_ws;                                 // 2 MB
    float* beta_ws = uh_ws + 4096 * 128;                           // 0.5 MB
    unsigned short* Whi = (unsigned short*)(beta_ws + 4096 * 32);  // 8 KB
    float* partial = (float*)(Whi + 4096);
    const size_t fixed_bytes = ((char*)partial) - ((char*)d_ws);

    int nsplit = 1, direct = 1;
    if (ws_size >= fixed_bytes + (size_t)256 * 4 * 2560 * 4) { nsplit = 4; direct = 0; }
    else if (ws_size >= fixed_bytes + (size_t)256 * 2 * 2560 * 4) { nsplit = 2; direct = 0; }
    else if (ws_size >= fixed_bytes + (size_t)256 * 1 * 2560 * 4) { nsplit = 1; direct = 0; }

    k1_gemm<<<dim3(256 * nsplit), dim3(256), 0, stream>>>(
        hidden, U_w, fb_w, W_w, U_b, W_b, fb_b,
        uh_ws, beta_ws, Whi, partial, nsplit, direct);
    if (!direct)
        k1b_reduce<<<dim3(640), dim3(256), 0, stream>>>(
            partial, U_b, W_b, fb_b, uh_ws, beta_ws, nsplit);
    k2_attn<<<dim3(2048), dim3(256), 0, stream>>>(img, Whi, v_w, uh_ws, beta_ws, out);
}

// Round 11
// 196.336 us; speedup vs baseline: 1.1138x; 1.1138x over previous
//
#include <hip/hip_runtime.h>
#include <hip/hip_bf16.h>

// B=4096, C=32, P=196, ENC=512, ATT=128. fp32 I/O.
// R2: k0 folded into k1 (in-register hi/lo split of B); k1b float4 (-3us).
// R7: k2 reverted to R2 form after R5's 2-batch global_load_lds pipeline
// regressed +16.7us (bank conflicts 3.3M, occupancy 27%, repack VALU).
// R8: k2 Phase B latency attack, layout unchanged: (1) 16-lane score
// reduce via DPP row_ror rotate-add (VALU, ~4cyc/step) instead of
// __shfl_xor/ds_swizzle (~55cyc/step, depth 4); lane l16==0 association
// tree identical to xor butterfly -> stored scores bit-identical.
// (2) A-frag ds_read prefetched one mt-iteration ahead.
// PIPE BUDGET (R7 recompute; 16 waves/SIMD lifetime): trans 5.5us, VALU
// ~8us, LDS ~3us, HBM ~13us (half of img L3-hot: FETCH=51.5MB not 103).
// k2 ~58us vs ~16us overlap floor at FULL occupancy -> dependent-chain
// latency is the gap, not any pipe.
// LESSONS: (R5/R6 prev) waves/EU >= 6 => scratch-spill storm; allocator
// pins 64 VGPR to hold 8 waves/SIMD -- structures needing more silently
// reorder instead (R10 hoist no-op). (R9 prev) harness poison fill (59us,
// 392MB) + restore in-window; fills own rocprof top-5 below 59us ->
// attribute via dur_us. (R10 prev) runtime-loop reduce prologue = +35us.
// (R7) at 8 blocks/CU the HW scheduler staggers blocks across phases;
// intra-block cross-batch pipelining buys nothing.

typedef __attribute__((ext_vector_type(8))) __bf16 bf16x8;
typedef __attribute__((ext_vector_type(4))) float floatx4;
typedef __attribute__((ext_vector_type(4))) unsigned int uint4v;

#define K2E 2.8853900817779268f   // 2*log2(e)

#if __has_builtin(__builtin_amdgcn_exp2f)
#define EXP2F(x) __builtin_amdgcn_exp2f(x)
#else
#define EXP2F(x) __expf(0.6931471805599453f * (x))
#endif

// DPP row_ror rotate-reduce step: s += ror16(s, N). VALU-only; within the
// 16-lane row this is a butterfly-equivalent tree on lane 0 of each group.
#define DPP_ROR_ADD(s, ctrl) do {                                            \
    int _t = __builtin_amdgcn_update_dpp(                                    \
        0, __builtin_bit_cast(int, (s)), (ctrl), 0xF, 0xF, true);            \
    (s) += __builtin_bit_cast(float, _t); } while (0)

static __device__ __forceinline__ float bf2f(unsigned short u) {
    union { unsigned int i; float f; } v; v.i = ((unsigned int)u) << 16; return v.f;
}
static __device__ __forceinline__ unsigned short f2bf(float f) {
    union { float f; unsigned int i; } v; v.f = f;
    unsigned int r = v.i + 0x7FFFu + ((v.i >> 16) & 1u);  // RNE
    return (unsigned short)(r >> 16);
}
static __device__ __forceinline__ float sigmoid_rcp(float x) {
    return __builtin_amdgcn_rcpf(1.0f + __expf(-x));
}
// Truncation hi/lo split of 8 contiguous fp32 (16B-aligned).
static __device__ __forceinline__ void split_trunc8(const float* src, bf16x8* hi, bf16x8* lo) {
    uint4v u0 = *(const uint4v*)src;
    uint4v u1 = *(const uint4v*)(src + 4);
    unsigned int fb[8], lb[8];
#pragma unroll
    for (int j = 0; j < 4; j++) { fb[j] = u0[j]; fb[4 + j] = u1[j]; }
#pragma unroll
    for (int k = 0; k < 8; k++) {
        float x = __uint_as_float(fb[k]);
        float h = __uint_as_float(fb[k] & 0xFFFF0000u);
        lb[k] = __float_as_uint(x - h);               // exact residual
    }
    uint4v hp, lp;
#pragma unroll
    for (int j = 0; j < 4; j++) {
        hp[j] = __builtin_amdgcn_perm(fb[2 * j + 1], fb[2 * j], 0x07060302u);
        lp[j] = __builtin_amdgcn_perm(lb[2 * j + 1], lb[2 * j], 0x07060302u);
    }
    *hi = __builtin_bit_cast(bf16x8, hp);
    *lo = __builtin_bit_cast(bf16x8, lp);
}

// ---------------------------------------------------------------------------
// k1: partial GEMM hidden @ [U_w;fb_w]^T, split-K (ws-gated), in-register
// hi/lo split of BOTH operands from fp32. Side-job: Whi = bf16(K2E*W_w).
// ---------------------------------------------------------------------------
__global__ __launch_bounds__(256) void k1_gemm(
    const float* __restrict__ hidden,
    const float* __restrict__ U_w, const float* __restrict__ fb_w,
    const float* __restrict__ W_w,
    const float* __restrict__ U_b, const float* __restrict__ W_b,
    const float* __restrict__ fb_b,
    float* __restrict__ uh_out, float* __restrict__ beta_out,
    unsigned short* __restrict__ Whi,
    float* __restrict__ partial, int nsplit, int direct)
{
    __shared__ float s_part[4 * 2560];
    const int tid = threadIdx.x;
    {
        const int gi = blockIdx.x * 256 + tid;
        if (gi < 4096) Whi[gi] = f2bf(W_w[gi] * K2E);
    }
    const int wave = tid >> 6, lane = tid & 63, quad = lane >> 4, l16 = lane & 15;
    const int mtile = blockIdx.x / nsplit;
    const int kblock = 512 / nsplit;
    const int ks0 = (blockIdx.x % nsplit) * kblock + wave * (kblock >> 2);
    const int ksteps = kblock >> 7;
    const int arow = mtile * 16 + l16;

    floatx4 acc[10];
#pragma unroll
    for (int i = 0; i < 10; i++) acc[i] = (floatx4)(0.0f);

    for (int ksi = 0; ksi < ksteps; ksi++) {
        const int e0 = ks0 + ksi * 32 + quad * 8;
        bf16x8 ah, al;
        split_trunc8(hidden + (size_t)arow * 512 + e0, &ah, &al);
#pragma unroll
        for (int n = 0; n < 10; n++) {
            const float* bsrc = (n < 8)
                ? (U_w  + (size_t)(n * 16 + l16) * 512 + e0)
                : (fb_w + (size_t)((n - 8) * 16 + l16) * 512 + e0);
            bf16x8 bh, bl;
            split_trunc8(bsrc, &bh, &bl);
            acc[n] = __builtin_amdgcn_mfma_f32_16x16x32_bf16(ah, bl, acc[n], 0, 0, 0);
            acc[n] = __builtin_amdgcn_mfma_f32_16x16x32_bf16(al, bh, acc[n], 0, 0, 0);
            acc[n] = __builtin_amdgcn_mfma_f32_16x16x32_bf16(ah, bh, acc[n], 0, 0, 0);
        }
    }
#pragma unroll
    for (int n = 0; n < 10; n++)
#pragma unroll
        for (int r = 0; r < 4; r++)
            s_part[wave * 2560 + (quad * 4 + r) * 160 + n * 16 + l16] = acc[n][r];
    __syncthreads();

#pragma unroll
    for (int j = 0; j < 10; j++) {
        const int i = tid + j * 256;
        float v = s_part[i] + s_part[2560 + i] + s_part[5120 + i] + s_part[7680 + i];
        if (direct) {
            const int m = mtile * 16 + i / 160, col = i % 160;
            if (col < 128) uh_out[(size_t)m * 128 + col] = K2E * (v + U_b[col] + W_b[col]);
            else beta_out[(size_t)m * 32 + (col - 128)] = sigmoid_rcp(v + fb_b[col - 128]);
        } else {
            partial[(size_t)blockIdx.x * 2560 + i] = v;
        }
    }
}

// k1b: float4-vectorized split-K reduce. 640 blocks x 256 thr.
__global__ __launch_bounds__(256) void k1b_reduce(
    const float* __restrict__ partial,
    const float* __restrict__ U_b, const float* __restrict__ W_b,
    const float* __restrict__ fb_b,
    float* __restrict__ uh_out, float* __restrict__ beta_out, int nsplit)
{
    const int idx = blockIdx.x * 256 + threadIdx.x;
    const int mt = idx / 640;
    const int r4 = (idx - mt * 640) * 4;
    floatx4 v = (floatx4)(0.0f);
    for (int s = 0; s < nsplit; s++) {
        const floatx4 p = *(const floatx4*)(partial + (size_t)(mt * nsplit + s) * 2560 + r4);
#pragma unroll
        for (int j = 0; j < 4; j++) v[j] += p[j];
    }
    const int m = mt * 16 + r4 / 160, col = r4 % 160;
    if (col < 128) {
        const floatx4 ub = *(const floatx4*)(U_b + col);
        const floatx4 wb = *(const floatx4*)(W_b + col);
        floatx4 o;
#pragma unroll
        for (int j = 0; j < 4; j++) o[j] = K2E * (v[j] + ub[j] + wb[j]);
        *(floatx4*)(uh_out + (size_t)m * 128 + col) = o;
    } else {
        const floatx4 fb = *(const floatx4*)(fb_b + (col - 128));
        floatx4 o;
#pragma unroll
        for (int j = 0; j < 4; j++) o[j] = sigmoid_rcp(v[j] + fb[j]);
        *(floatx4*)(beta_out + (size_t)m * 32 + (col - 128)) = o;
    }
}

// ---------------------------------------------------------------------------
// k2: one block (256 thr) per batch. M=p (13 tiles), N=a (8 tiles), K=c.
// Max-free softmax: Phase B emits e = exp(score) directly; 3 barriers.
// R8: DPP rotate-reduce + A-frag prefetch in Phase B.
// ---------------------------------------------------------------------------
#define HSTR 40    // u16 per LDS img row (32 data + 8 pad; 80 B -> ~2-way banks)

__global__ __launch_bounds__(256, 4) void k2_attn(
    const float* __restrict__ img,            // [4096][32][196]
    const unsigned short* __restrict__ Whi,   // [128][32] bf16 (pre-scaled K2E)
    const float* __restrict__ v_w,            // [128]
    const float* __restrict__ uh,             // [4096][128] (scaled K2E, biases in)
    const float* __restrict__ beta,           // [4096][32]
    float* __restrict__ out)
{
    __shared__ __align__(16) unsigned short s_imgh[208 * HSTR];  // 16640 B
    __shared__ float s_score[208];   // holds e[p] (unnormalized softmax)
    __shared__ float s_red[4];
    __shared__ float s_ctx[4][32];

    const int tid = threadIdx.x;
    const int b = blockIdx.x;
    const int wave = tid >> 6, lane = tid & 63, quad = lane >> 4, l16 = lane & 15;

    // ---- Phase A: transpose-stage img[b] -> LDS bf16-RNE [p][c] ----
    if (tid < 196) {
        const size_t base = (size_t)b * 6272 + tid;
#pragma unroll
        for (int g = 0; g < 4; g++) {
            unsigned int hb[8];
#pragma unroll
            for (int j = 0; j < 8; j++) {
                unsigned int u = __float_as_uint(img[base + (size_t)(8 * g + j) * 196]);
                hb[j] = u + 0x7FFFu + ((u >> 16) & 1u);   // RNE to bf16 in hi16
            }
            uint4v hp;
#pragma unroll
            for (int j = 0; j < 4; j++)
                hp[j] = __builtin_amdgcn_perm(hb[2 * j + 1], hb[2 * j], 0x07060302u);
            *(uint4v*)&s_imgh[tid * HSTR + g * 8] = hp;   // ds_write_b128
        }
    } else {
        for (int i = tid - 196; i < 12 * HSTR; i += 60) s_imgh[196 * HSTR + i] = 0;
        if (tid < 208) s_score[tid] = 0.0f;   // rows 196..207 weight 0 for Phase D
    }

    // per-lane uh (scaled) and v; Sv = sum_a v[a]
    float uaR[8], va2R[8], sv = 0.0f;
#pragma unroll
    for (int nt = 0; nt < 8; nt++) {
        uaR[nt] = uh[(size_t)b * 128 + nt * 16 + l16];
        float v = v_w[nt * 16 + l16];
        sv += v;
        va2R[nt] = -2.0f * v;
    }
    sv += __shfl_xor(sv, 1); sv += __shfl_xor(sv, 2);
    sv += __shfl_xor(sv, 4); sv += __shfl_xor(sv, 8);   // uniform over l16
    __syncthreads();   // barrier 1: img + s_score pad ready

    // ---- Phase B: wave w owns p-tiles {w, w+4, w+8 (,12)}; emit e directly.
    // |score| <= sum|v_a| (~5): exp(score) cannot overflow -> no max pass.
    float esum = 0.0f;
    bf16x8 a = *(const bf16x8*)&s_imgh[(wave * 16 + l16) * HSTR + quad * 8];
    for (int mt = wave; mt < 13; mt += 4) {
        // prefetch next tile's A-frag; rides as an outstanding ds_read
        bf16x8 a_next = a;
        if (mt + 4 < 13)
            a_next = *(const bf16x8*)&s_imgh[((mt + 4) * 16 + l16) * HSTR + quad * 8];

        float sc4[4] = {0.f, 0.f, 0.f, 0.f};
#pragma unroll
        for (int nt = 0; nt < 8; nt++) {
            bf16x8 bh = *(const bf16x8*)(Whi + (nt * 16 + l16) * 32 + quad * 8);
            const float ua = uaR[nt];
            floatx4 d = {ua, ua, ua, ua};            // fold Uh(+biases) into C
            d = __builtin_amdgcn_mfma_f32_16x16x32_bf16(a, bh, d, 0, 0, 0);
#pragma unroll
            for (int r = 0; r < 4; r++) {
                float e = EXP2F(d[r]);                         // e^{2x}
                float rr = __builtin_amdgcn_rcpf(1.0f + e);
                sc4[r] = __builtin_fmaf(va2R[nt], rr, sc4[r]); // -2 v_a r
            }
        }
#pragma unroll
        for (int r = 0; r < 4; r++) {
            float s = sc4[r];
            DPP_ROR_ADD(s, 0x121);   // += ror1  (VALU; lane0 tree == xor tree)
            DPP_ROR_ADD(s, 0x122);   // += ror2
            DPP_ROR_ADD(s, 0x124);   // += ror4
            DPP_ROR_ADD(s, 0x128);   // += ror8
            const int p = mt * 16 + quad * 4 + r;
            if (l16 == 0 && p < 196) {
                float e = __expf(sv + s);
                s_score[p] = e;
                esum += e;
            }
        }
        a = a_next;
    }
    // esum lives in l16==0 lanes (0,16,32,48); fold across quads -> lane 0
    esum += __shfl_xor(esum, 16);
    esum += __shfl_xor(esum, 32);
    if (lane == 0) s_red[wave] = esum;
    __syncthreads();   // barrier 2: e[p] + per-wave sums ready

    const float tot = s_red[0] + s_red[1] + s_red[2] + s_red[3];
    const float rtot = __builtin_amdgcn_rcpf(tot);
    if (tid < 196)
        out[131072 + (size_t)b * 196 + tid] = s_score[tid] * rtot;   // att_weights

    // ---- Phase D: context[c] = beta[c]/tot * sum_p img[p][c]*e[p] ----
    {
        const int c = lane & 31;
        const int po = wave * 2 + (lane >> 5);   // 0..7
        float acc = 0.0f;
#pragma unroll 5
        for (int j = 0; j < 25; j++) {
            const int p = po + j * 8;            // <=199; rows 196+ zeroed
            acc = __builtin_fmaf(bf2f(s_imgh[p * HSTR + c]), s_score[p], acc);
        }
        acc += __shfl_xor(acc, 32);
        if ((lane >> 5) == 0) s_ctx[wave][c] = acc;
    }
    __syncthreads();   // barrier 3: ctx partials ready
    if (tid < 32) {
        const float v = s_ctx[0][tid] + s_ctx[1][tid] + s_ctx[2][tid] + s_ctx[3][tid];
        out[(size_t)b * 32 + tid] = v * rtot * beta[(size_t)b * 32 + tid];
    }
}

extern "C" void kernel_launch(void* const* d_in, const int* in_sizes, int n_in,
                              void* d_out, int out_size, void* d_ws, size_t ws_size,
                              hipStream_t stream) {
    const float* img    = (const float*)d_in[0];
    const float* hidden = (const float*)d_in[1];
    const float* W_w    = (const float*)d_in[2];
    const float* W_b    = (const float*)d_in[3];
    const float* U_w    = (const float*)d_in[4];
    const float* U_b    = (const float*)d_in[5];
    const float* v_w    = (const float*)d_in[6];
    // d_in[7] = v_b: cancels in softmax
    const float* fb_w   = (const float*)d_in[8];
    const float* fb_b   = (const float*)d_in[9];
    float* out = (float*)d_out;

    float* uh_ws   = (float*)d_ws;                                 // 2 MB
    float* beta_ws = uh_ws + 4096 * 128;                           // 0.5 MB
    unsigned short* Whi = (unsigned short*)(beta_ws + 4096 * 32);  // 8 KB
    float* partial = (float*)(Whi + 4096);
    const size_t fixed_bytes = ((char*)partial) - ((char*)d_ws);

    int nsplit = 1, direct = 1;
    if (ws_size >= fixed_bytes + (size_t)256 * 4 * 2560 * 4) { nsplit = 4; direct = 0; }
    else if (ws_size >= fixed_bytes + (size_t)256 * 2 * 2560 * 4) { nsplit = 2; direct = 0; }
    else if (ws_size >= fixed_bytes + (size_t)256 * 1 * 2560 * 4) { nsplit = 1; direct = 0; }

    k1_gemm<<<dim3(256 * nsplit), dim3(256), 0, stream>>>(
        hidden, U_w, fb_w, W_w, U_b, W_b, fb_b,
        uh_ws, beta_ws, Whi, partial, nsplit, direct);
    if (!direct)
        k1b_reduce<<<dim3(640), dim3(256), 0, stream>>>(
            partial, U_b, W_b, fb_b, uh_ws, beta_ws, nsplit);
    k2_attn<<<dim3(4096), dim3(256), 0, stream>>>(img, Whi, v_w, uh_ws, beta_ws, out);
}

// Round 16
// 196.245 us; speedup vs baseline: 1.1143x; 1.0005x over previous
//
#include <hip/hip_runtime.h>
#include <hip/hip_bf16.h>

// B=4096, C=32, P=196, ENC=512, ATT=128. fp32 I/O.
// R2: k0 folded into k1 (in-register hi/lo split of B); k1b float4 (-3us).
// R7: k2 reverted after R5 regression (+16.7us: conflicts/occupancy/repack).
// R8 (MEASURED -5.6us, 202.0->196.3, PASSED full post-timing checks):
// DPP row_ror rotate-add score reduce + A-frag prefetch. Chain-latency
// theory CONFIRMED.
// R11 FAILED post-timing (bundle: launch_bounds(256,3) + bhR hoist +
// Phase D dual-chain). No defect found in audit; mechanism unexplained.
// RULE: 64-VGPR / 8-blocks-per-CU envelope is validated; leave only with
// a mechanism.
// R15: ISOLATION TEST -- Phase D dual-chain ALONE on the R8 base
// (launch_bounds stays (256,4); no hoist). If this fails post-timing,
// dual-chain caused R11's divergence; if it passes, the occupancy shift
// did. Also expected -0.5..-2us (Phase D fma chain 100->52 cyc).
// LESSONS: (R5/R6 prev) waves/EU >= 6 => spill storm. (R9 prev) harness
// fill 59-61us owns rocprof top-5; k2 ~52.5us invisible -> attribute via
// dur_us. (R10 prev) runtime-loop reduce prologue = +35us; keep k1b.
// (R7) HW scheduler staggers blocks; cross-batch pipelining buys nothing.
// (R14) single-variable discipline: R11's 3-way bundle destroyed
// attribution; never bundle again.
// MODEL GAP (open): pipe sums say k2 ~16us; measured 52.5 ->
// issue/latency-bound at full occupancy.

typedef __attribute__((ext_vector_type(8))) __bf16 bf16x8;
typedef __attribute__((ext_vector_type(4))) float floatx4;
typedef __attribute__((ext_vector_type(4))) unsigned int uint4v;

#define K2E 2.8853900817779268f   // 2*log2(e)

#if __has_builtin(__builtin_amdgcn_exp2f)
#define EXP2F(x) __builtin_amdgcn_exp2f(x)
#else
#define EXP2F(x) __expf(0.6931471805599453f * (x))
#endif

// DPP row_ror rotate-reduce step: s += ror16(s, N). VALU-only; within the
// 16-lane row this is a butterfly-equivalent tree on lane 0 of each group.
#define DPP_ROR_ADD(s, ctrl) do {                                            \
    int _t = __builtin_amdgcn_update_dpp(                                    \
        0, __builtin_bit_cast(int, (s)), (ctrl), 0xF, 0xF, true);            \
    (s) += __builtin_bit_cast(float, _t); } while (0)

static __device__ __forceinline__ float bf2f(unsigned short u) {
    union { unsigned int i; float f; } v; v.i = ((unsigned int)u) << 16; return v.f;
}
static __device__ __forceinline__ unsigned short f2bf(float f) {
    union { float f; unsigned int i; } v; v.f = f;
    unsigned int r = v.i + 0x7FFFu + ((v.i >> 16) & 1u);  // RNE
    return (unsigned short)(r >> 16);
}
static __device__ __forceinline__ float sigmoid_rcp(float x) {
    return __builtin_amdgcn_rcpf(1.0f + __expf(-x));
}
// Truncation hi/lo split of 8 contiguous fp32 (16B-aligned).
static __device__ __forceinline__ void split_trunc8(const float* src, bf16x8* hi, bf16x8* lo) {
    uint4v u0 = *(const uint4v*)src;
    uint4v u1 = *(const uint4v*)(src + 4);
    unsigned int fb[8], lb[8];
#pragma unroll
    for (int j = 0; j < 4; j++) { fb[j] = u0[j]; fb[4 + j] = u1[j]; }
#pragma unroll
    for (int k = 0; k < 8; k++) {
        float x = __uint_as_float(fb[k]);
        float h = __uint_as_float(fb[k] & 0xFFFF0000u);
        lb[k] = __float_as_uint(x - h);               // exact residual
    }
    uint4v hp, lp;
#pragma unroll
    for (int j = 0; j < 4; j++) {
        hp[j] = __builtin_amdgcn_perm(fb[2 * j + 1], fb[2 * j], 0x07060302u);
        lp[j] = __builtin_amdgcn_perm(lb[2 * j + 1], lb[2 * j], 0x07060302u);
    }
    *hi = __builtin_bit_cast(bf16x8, hp);
    *lo = __builtin_bit_cast(bf16x8, lp);
}

// ---------------------------------------------------------------------------
// k1: partial GEMM hidden @ [U_w;fb_w]^T, split-K (ws-gated), in-register
// hi/lo split of BOTH operands from fp32. Side-job: Whi = bf16(K2E*W_w).
// ---------------------------------------------------------------------------
__global__ __launch_bounds__(256) void k1_gemm(
    const float* __restrict__ hidden,
    const float* __restrict__ U_w, const float* __restrict__ fb_w,
    const float* __restrict__ W_w,
    const float* __restrict__ U_b, const float* __restrict__ W_b,
    const float* __restrict__ fb_b,
    float* __restrict__ uh_out, float* __restrict__ beta_out,
    unsigned short* __restrict__ Whi,
    float* __restrict__ partial, int nsplit, int direct)
{
    __shared__ float s_part[4 * 2560];
    const int tid = threadIdx.x;
    {
        const int gi = blockIdx.x * 256 + tid;
        if (gi < 4096) Whi[gi] = f2bf(W_w[gi] * K2E);
    }
    const int wave = tid >> 6, lane = tid & 63, quad = lane >> 4, l16 = lane & 15;
    const int mtile = blockIdx.x / nsplit;
    const int kblock = 512 / nsplit;
    const int ks0 = (blockIdx.x % nsplit) * kblock + wave * (kblock >> 2);
    const int ksteps = kblock >> 7;
    const int arow = mtile * 16 + l16;

    floatx4 acc[10];
#pragma unroll
    for (int i = 0; i < 10; i++) acc[i] = (floatx4)(0.0f);

    for (int ksi = 0; ksi < ksteps; ksi++) {
        const int e0 = ks0 + ksi * 32 + quad * 8;
        bf16x8 ah, al;
        split_trunc8(hidden + (size_t)arow * 512 + e0, &ah, &al);
#pragma unroll
        for (int n = 0; n < 10; n++) {
            const float* bsrc = (n < 8)
                ? (U_w  + (size_t)(n * 16 + l16) * 512 + e0)
                : (fb_w + (size_t)((n - 8) * 16 + l16) * 512 + e0);
            bf16x8 bh, bl;
            split_trunc8(bsrc, &bh, &bl);
            acc[n] = __builtin_amdgcn_mfma_f32_16x16x32_bf16(ah, bl, acc[n], 0, 0, 0);
            acc[n] = __builtin_amdgcn_mfma_f32_16x16x32_bf16(al, bh, acc[n], 0, 0, 0);
            acc[n] = __builtin_amdgcn_mfma_f32_16x16x32_bf16(ah, bh, acc[n], 0, 0, 0);
        }
    }
#pragma unroll
    for (int n = 0; n < 10; n++)
#pragma unroll
        for (int r = 0; r < 4; r++)
            s_part[wave * 2560 + (quad * 4 + r) * 160 + n * 16 + l16] = acc[n][r];
    __syncthreads();

#pragma unroll
    for (int j = 0; j < 10; j++) {
        const int i = tid + j * 256;
        float v = s_part[i] + s_part[2560 + i] + s_part[5120 + i] + s_part[7680 + i];
        if (direct) {
            const int m = mtile * 16 + i / 160, col = i % 160;
            if (col < 128) uh_out[(size_t)m * 128 + col] = K2E * (v + U_b[col] + W_b[col]);
            else beta_out[(size_t)m * 32 + (col - 128)] = sigmoid_rcp(v + fb_b[col - 128]);
        } else {
            partial[(size_t)blockIdx.x * 2560 + i] = v;
        }
    }
}

// k1b: float4-vectorized split-K reduce. 640 blocks x 256 thr.
__global__ __launch_bounds__(256) void k1b_reduce(
    const float* __restrict__ partial,
    const float* __restrict__ U_b, const float* __restrict__ W_b,
    const float* __restrict__ fb_b,
    float* __restrict__ uh_out, float* __restrict__ beta_out, int nsplit)
{
    const int idx = blockIdx.x * 256 + threadIdx.x;
    const int mt = idx / 640;
    const int r4 = (idx - mt * 640) * 4;
    floatx4 v = (floatx4)(0.0f);
    for (int s = 0; s < nsplit; s++) {
        const floatx4 p = *(const floatx4*)(partial + (size_t)(mt * nsplit + s) * 2560 + r4);
#pragma unroll
        for (int j = 0; j < 4; j++) v[j] += p[j];
    }
    const int m = mt * 16 + r4 / 160, col = r4 % 160;
    if (col < 128) {
        const floatx4 ub = *(const floatx4*)(U_b + col);
        const floatx4 wb = *(const floatx4*)(W_b + col);
        floatx4 o;
#pragma unroll
        for (int j = 0; j < 4; j++) o[j] = K2E * (v[j] + ub[j] + wb[j]);
        *(floatx4*)(uh_out + (size_t)m * 128 + col) = o;
    } else {
        const floatx4 fb = *(const floatx4*)(fb_b + (col - 128));
        floatx4 o;
#pragma unroll
        for (int j = 0; j < 4; j++) o[j] = sigmoid_rcp(v[j] + fb[j]);
        *(floatx4*)(beta_out + (size_t)m * 32 + (col - 128)) = o;
    }
}

// ---------------------------------------------------------------------------
// k2: one block (256 thr) per batch. M=p (13 tiles), N=a (8 tiles), K=c.
// Max-free softmax: Phase B emits e = exp(score) directly; 3 barriers.
// R8: DPP rotate-reduce + A-frag prefetch. R15: Phase D dual-chain ONLY.
// ---------------------------------------------------------------------------
#define HSTR 40    // u16 per LDS img row (32 data + 8 pad; 80 B -> ~2-way banks)

__global__ __launch_bounds__(256, 4) void k2_attn(
    const float* __restrict__ img,            // [4096][32][196]
    const unsigned short* __restrict__ Whi,   // [128][32] bf16 (pre-scaled K2E)
    const float* __restrict__ v_w,            // [128]
    const float* __restrict__ uh,             // [4096][128] (scaled K2E, biases in)
    const float* __restrict__ beta,           // [4096][32]
    float* __restrict__ out)
{
    __shared__ __align__(16) unsigned short s_imgh[208 * HSTR];  // 16640 B
    __shared__ float s_score[208];   // holds e[p] (unnormalized softmax)
    __shared__ float s_red[4];
    __shared__ float s_ctx[4][32];

    const int tid = threadIdx.x;
    const int b = blockIdx.x;
    const int wave = tid >> 6, lane = tid & 63, quad = lane >> 4, l16 = lane & 15;

    // ---- Phase A: transpose-stage img[b] -> LDS bf16-RNE [p][c] ----
    if (tid < 196) {
        const size_t base = (size_t)b * 6272 + tid;
#pragma unroll
        for (int g = 0; g < 4; g++) {
            unsigned int hb[8];
#pragma unroll
            for (int j = 0; j < 8; j++) {
                unsigned int u = __float_as_uint(img[base + (size_t)(8 * g + j) * 196]);
                hb[j] = u + 0x7FFFu + ((u >> 16) & 1u);   // RNE to bf16 in hi16
            }
            uint4v hp;
#pragma unroll
            for (int j = 0; j < 4; j++)
                hp[j] = __builtin_amdgcn_perm(hb[2 * j + 1], hb[2 * j], 0x07060302u);
            *(uint4v*)&s_imgh[tid * HSTR + g * 8] = hp;   // ds_write_b128
        }
    } else {
        for (int i = tid - 196; i < 12 * HSTR; i += 60) s_imgh[196 * HSTR + i] = 0;
        if (tid < 208) s_score[tid] = 0.0f;   // rows 196..207 weight 0 for Phase D
    }

    // per-lane uh (scaled) and v; Sv = sum_a v[a]
    float uaR[8], va2R[8], sv = 0.0f;
#pragma unroll
    for (int nt = 0; nt < 8; nt++) {
        uaR[nt] = uh[(size_t)b * 128 + nt * 16 + l16];
        float v = v_w[nt * 16 + l16];
        sv += v;
        va2R[nt] = -2.0f * v;
    }
    sv += __shfl_xor(sv, 1); sv += __shfl_xor(sv, 2);
    sv += __shfl_xor(sv, 4); sv += __shfl_xor(sv, 8);   // uniform over l16
    __syncthreads();   // barrier 1: img + s_score pad ready

    // ---- Phase B: wave w owns p-tiles {w, w+4, w+8 (,12)}; emit e directly.
    // |score| <= sum|v_a| (~5): exp(score) cannot overflow -> no max pass.
    float esum = 0.0f;
    bf16x8 a = *(const bf16x8*)&s_imgh[(wave * 16 + l16) * HSTR + quad * 8];
    for (int mt = wave; mt < 13; mt += 4) {
        // prefetch next tile's A-frag; rides as an outstanding ds_read
        bf16x8 a_next = a;
        if (mt + 4 < 13)
            a_next = *(const bf16x8*)&s_imgh[((mt + 4) * 16 + l16) * HSTR + quad * 8];

        float sc4[4] = {0.f, 0.f, 0.f, 0.f};
#pragma unroll
        for (int nt = 0; nt < 8; nt++) {
            bf16x8 bh = *(const bf16x8*)(Whi + (nt * 16 + l16) * 32 + quad * 8);
            const float ua = uaR[nt];
            floatx4 d = {ua, ua, ua, ua};            // fold Uh(+biases) into C
            d = __builtin_amdgcn_mfma_f32_16x16x32_bf16(a, bh, d, 0, 0, 0);
#pragma unroll
            for (int r = 0; r < 4; r++) {
                float e = EXP2F(d[r]);                         // e^{2x}
                float rr = __builtin_amdgcn_rcpf(1.0f + e);
                sc4[r] = __builtin_fmaf(va2R[nt], rr, sc4[r]); // -2 v_a r
            }
        }
#pragma unroll
        for (int r = 0; r < 4; r++) {
            float s = sc4[r];
            DPP_ROR_ADD(s, 0x121);   // += ror1  (VALU; lane0 tree == xor tree)
            DPP_ROR_ADD(s, 0x122);   // += ror2
            DPP_ROR_ADD(s, 0x124);   // += ror4
            DPP_ROR_ADD(s, 0x128);   // += ror8
            const int p = mt * 16 + quad * 4 + r;
            if (l16 == 0 && p < 196) {
                float e = __expf(sv + s);
                s_score[p] = e;
                esum += e;
            }
        }
        a = a_next;
    }
    // esum lives in l16==0 lanes (0,16,32,48); fold across quads -> lane 0
    esum += __shfl_xor(esum, 16);
    esum += __shfl_xor(esum, 32);
    if (lane == 0) s_red[wave] = esum;
    __syncthreads();   // barrier 2: e[p] + per-wave sums ready

    const float tot = s_red[0] + s_red[1] + s_red[2] + s_red[3];
    const float rtot = __builtin_amdgcn_rcpf(tot);
    if (tid < 196)
        out[131072 + (size_t)b * 196 + tid] = s_score[tid] * rtot;   // att_weights

    // ---- Phase D: context[c] = beta[c]/tot * sum_p img[p][c]*e[p] ----
    // R15: two independent fma chains (13 + 12) for 2x ILP on the chain.
    // Coverage {po + 8k, k=0..24} identical to R8; fp reassociation only.
    {
        const int c = lane & 31;
        const int po = wave * 2 + (lane >> 5);   // 0..7
        float acc0 = 0.0f, acc1 = 0.0f;
#pragma unroll 6
        for (int j = 0; j < 12; j++) {
            const int p0 = po + (2 * j) * 8;     // even slots
            const int p1 = po + (2 * j + 1) * 8; // odd slots
            acc0 = __builtin_fmaf(bf2f(s_imgh[p0 * HSTR + c]), s_score[p0], acc0);
            acc1 = __builtin_fmaf(bf2f(s_imgh[p1 * HSTR + c]), s_score[p1], acc1);
        }
        {
            const int p = po + 24 * 8;           // <=199; rows 196+ zeroed
            acc0 = __builtin_fmaf(bf2f(s_imgh[p * HSTR + c]), s_score[p], acc0);
        }
        float acc = acc0 + acc1;
        acc += __shfl_xor(acc, 32);
        if ((lane >> 5) == 0) s_ctx[wave][c] = acc;
    }
    __syncthreads();   // barrier 3: ctx partials ready
    if (tid < 32) {
        const float v = s_ctx[0][tid] + s_ctx[1][tid] + s_ctx[2][tid] + s_ctx[3][tid];
        out[(size_t)b * 32 + tid] = v * rtot * beta[(size_t)b * 32 + tid];
    }
}

extern "C" void kernel_launch(void* const* d_in, const int* in_sizes, int n_in,
                              void* d_out, int out_size, void* d_ws, size_t ws_size,
                              hipStream_t stream) {
    const float* img    = (const float*)d_in[0];
    const float* hidden = (const float*)d_in[1];
    const float* W_w    = (const float*)d_in[2];
    const float* W_b    = (const float*)d_in[3];
    const float* U_w    = (const float*)d_in[4];
    const float* U_b    = (const float*)d_in[5];
    const float* v_w    = (const float*)d_in[6];
    // d_in[7] = v_b: cancels in softmax
    const float* fb_w   = (const float*)d_in[8];
    const float* fb_b   = (const float*)d_in[9];
    float* out = (float*)d_out;

    float* uh_ws   = (float*)d_ws;                                 // 2 MB
    float* beta_ws = uh_ws + 4096 * 128;                           // 0.5 MB
    unsigned short* Whi = (unsigned short*)(beta_ws + 4096 * 32);  // 8 KB
    float* partial = (float*)(Whi + 4096);
    const size_t fixed_bytes = ((char*)partial) - ((char*)d_ws);

    int nsplit = 1, direct = 1;
    if (ws_size >= fixed_bytes + (size_t)256 * 4 * 2560 * 4) { nsplit = 4; direct = 0; }
    else if (ws_size >= fixed_bytes + (size_t)256 * 2 * 2560 * 4) { nsplit = 2; direct = 0; }
    else if (ws_size >= fixed_bytes + (size_t)256 * 1 * 2560 * 4) { nsplit = 1; direct = 0; }

    k1_gemm<<<dim3(256 * nsplit), dim3(256), 0, stream>>>(
        hidden, U_w, fb_w, W_w, U_b, W_b, fb_b,
        uh_ws, beta_ws, Whi, partial, nsplit, direct);
    if (!direct)
        k1b_reduce<<<dim3(640), dim3(256), 0, stream>>>(
            partial, U_b, W_b, fb_b, uh_ws, beta_ws, nsplit);
    k2_attn<<<dim3(4096), dim3(256), 0, stream>>>(img, Whi, v_w, uh_ws, beta_ws, out);
}